// Round 27
// baseline (494.567 us; speedup 1.0000x reference)
//
#include <hip/hip_runtime.h>
#include <hip/hip_bf16.h>
#include <math.h>

#define NN   10000
#define EE   160000
#define CC   128
#define RBFD 20
#define HIDD 32
#define WND  384
#define MROW 1152   // 9*128 accumulator row: [m=0..8][c=0..127]
#define EPB  64     // edges per block

typedef _Float16 half2_t __attribute__((ext_vector_type(2)));

__device__ __forceinline__ half2_t u2h(unsigned int u)
{
    union { unsigned int u; half2_t h; } c; c.u = u; return c.h;
}
__device__ __forceinline__ unsigned int pack_h2(float a, float b)
{
    union { half2_t h; unsigned int u; } c;
    c.h.x = (_Float16)a; c.h.y = (_Float16)b; return c.u;
}

// Static device buffers. g_accu: starts zero (.bss); each call accumulates,
// lin2 re-zeroes after reading -> invariant "zero at call entry" holds.
__device__ __align__(16) float g_proj[(size_t)NN * 64];   // 2.6 MB
__device__ __align__(16) float g_accu[(size_t)NN * MROW]; // 46 MB
__device__ __align__(16) uint4 g_wp[3 * 16 * 64];         // 48 KB packed MLP2 weights
__device__ __align__(16) unsigned int g_lw[3 * 64 * 128]; // 96 KB packed lin2 weights
__device__ int g_deg[NN];
__device__ int g_offs[NN + 1];
__device__ int g_rel[EE];
__device__ int g_ord[EE];   // sorted row -> original edge

__device__ __forceinline__ float silu_f(float x) { return x / (1.f + __expf(-x)); }

// Pack MLP2 weights (layout [sec][kind][q][lane]) + lin2 weights + zero g_deg.
__global__ __launch_bounds__(192) void pack_kernel(
    const float* __restrict__ Ws2, const float* __restrict__ Wr2,
    const float* __restrict__ W0, const float* __restrict__ W1,
    const float* __restrict__ W2)
{
    int tid = threadIdx.x;          // 192 = 3 sec x 64 lanes
    for (int i = tid; i < NN; i += 192) g_deg[i] = 0;

    for (int idx = tid; idx < 3 * 64 * 128; idx += 192) {
        int mat = idx >> 13;
        int rem = idx & 8191;
        int c2 = rem >> 7;
        int d  = rem & 127;
        const float* Wm = (mat == 0) ? W0 : ((mat == 1) ? W1 : W2);
        g_lw[idx] = pack_h2(Wm[(2 * c2) * CC + d], Wm[(2 * c2 + 1) * CC + d]);
    }

    int sec = tid >> 6, l = tid & 63;
    int c0 = sec * 128 + 2 * l;
    #pragma unroll
    for (int q = 0; q < 4; ++q) {
        unsigned int w0[4], w1[4], r0[4], r1[4];
        #pragma unroll
        for (int i = 0; i < 4; ++i) {
            int p = 4 * q + i;
            int b0 = (2 * p) * WND + c0;
            int b1 = (2 * p + 1) * WND + c0;
            w0[i] = pack_h2(Ws2[b0],     Ws2[b1]);
            w1[i] = pack_h2(Ws2[b0 + 1], Ws2[b1 + 1]);
            r0[i] = pack_h2(Wr2[b0],     Wr2[b1]);
            r1[i] = pack_h2(Wr2[b0 + 1], Wr2[b1 + 1]);
        }
        g_wp[((sec * 16 + 0 * 4 + q) * 64) + l] = make_uint4(w0[0], w0[1], w0[2], w0[3]);
        g_wp[((sec * 16 + 1 * 4 + q) * 64) + l] = make_uint4(w1[0], w1[1], w1[2], w1[3]);
        g_wp[((sec * 16 + 2 * 4 + q) * 64) + l] = make_uint4(r0[0], r0[1], r0[2], r0[3]);
        g_wp[((sec * 16 + 3 * 4 + q) * 64) + l] = make_uint4(r1[0], r1[1], r1[2], r1[3]);
    }
}

__global__ __launch_bounds__(256) void hist_kernel(const int* __restrict__ edge_index)
{
    int e = blockIdx.x * 256 + threadIdx.x;
    if (e < EE) g_rel[e] = atomicAdd(&g_deg[edge_index[e]], 1);
}

// Blocked scan: 1024 threads x 10 items, one block.
__global__ __launch_bounds__(1024) void scan_kernel()
{
    __shared__ int sP[1024];
    int t = threadIdx.x;
    int lo = t * 10, hi = min(lo + 10, NN);
    int sum = 0;
    for (int i = lo; i < hi; ++i) sum += g_deg[i];
    sP[t] = sum;
    __syncthreads();
    for (int off = 1; off < 1024; off <<= 1) {
        int v = (t >= off) ? sP[t - off] : 0;
        __syncthreads();
        sP[t] += v;
        __syncthreads();
    }
    int run = sP[t] - sum;   // exclusive prefix
    if (t == 0) g_offs[0] = 0;
    for (int i = lo; i < hi; ++i) { run += g_deg[i]; g_offs[i + 1] = run; }
}

// MLP1 halves + edge permutation (grid is exactly EE threads).
__global__ __launch_bounds__(256) void proj_kernel(
    const float* __restrict__ nf,
    const float* __restrict__ Ws1, const float* __restrict__ bs1,
    const int* __restrict__ edge_index)
{
    __shared__ float sX[16][132];

    int tid = threadIdx.x;
    int nb = blockIdx.x * 16;       // grid exact: NN/16 = 625

    {
        int eg = blockIdx.x * 256 + tid;
        g_ord[g_offs[edge_index[eg]] + g_rel[eg]] = eg;
    }

    #pragma unroll
    for (int i = tid; i < 512; i += 256) {
        int n = i >> 5, k4 = i & 31;
        float4 v = reinterpret_cast<const float4*>(nf + (size_t)(nb + n) * CC)[k4];
        sX[n][k4 * 4 + 0] = v.x;
        sX[n][k4 * 4 + 1] = v.y;
        sX[n][k4 * 4 + 2] = v.z;
        sX[n][k4 * 4 + 3] = v.w;
    }
    __syncthreads();

    int nl = tid >> 4;
    int qd = tid & 15;
    int j0 = (qd & 7) * 4;
    int rbase = (qd >= 8) ? CC : 0;

    float4 acc;
    if (qd < 8) acc = *reinterpret_cast<const float4*>(&bs1[j0]);
    else        acc = make_float4(0.f, 0.f, 0.f, 0.f);

    const float* wb = Ws1 + (size_t)rbase * HIDD + j0;
    #pragma unroll 4
    for (int k = 0; k < CC; ++k) {
        float f = sX[nl][k];
        float4 w = *reinterpret_cast<const float4*>(wb + (size_t)k * HIDD);
        acc.x = fmaf(f, w.x, acc.x);
        acc.y = fmaf(f, w.y, acc.y);
        acc.z = fmaf(f, w.z, acc.z);
        acc.w = fmaf(f, w.w, acc.w);
    }

    float* o = g_proj + (size_t)(nb + nl) * 64 + ((qd >= 8) ? HIDD : 0) + j0;
    *reinterpret_cast<float4*>(o) = acc;
}

// One 128-col section over EPB sorted edges, EDGE-PAIRED (ET=2): per q-step
// load 4 uint4 weights once and apply to 2 edges -> 8 weight VMEM/edge (was
// 16 under remat). Peak live set ~50 words -> fits the 60-VGPR envelope.
template<int K, int YB, int MOFF>
__device__ __forceinline__ void section_pass(
    int sec, int l,
    const float2* __restrict__ nf2,
    const float* __restrict__ bs2, const float* __restrict__ br2,
    const unsigned int (*__restrict__ sH)[36], const float (*__restrict__ sY)[9],
    const int* __restrict__ sSrc, const int* __restrict__ sDst)
{
    const uint4* wt = g_wp + (size_t)sec * 16 * 64 + l;   // stride 64 per slot
    float2 bsv = *reinterpret_cast<const float2*>(&bs2[sec * 128 + 2 * l]);
    float2 brv = *reinterpret_cast<const float2*>(&br2[sec * 128 + 2 * l]);

    float racc0[K], racc1[K];
    #pragma unroll
    for (int k = 0; k < K; ++k) { racc0[k] = 0.f; racc1[k] = 0.f; }
    int cur = sSrc[0];

    #pragma unroll 2
    for (int et = 0; et < EPB / 2; ++et) {
        int iA = 2 * et, iB = 2 * et + 1;
        float asA0 = bsv.x, asA1 = bsv.y, arA0 = brv.x, arA1 = brv.y;
        float asB0 = bsv.x, asB1 = bsv.y, arB0 = brv.x, arB1 = brv.y;
        const uint4* hpA = reinterpret_cast<const uint4*>(&sH[iA][0]);
        const uint4* hpB = reinterpret_cast<const uint4*>(&sH[iB][0]);
        #pragma unroll
        for (int q = 0; q < 4; ++q) {
            uint4 w0q = wt[(0 * 4 + q) * 64];
            uint4 w1q = wt[(1 * 4 + q) * 64];
            uint4 r0q = wt[(2 * 4 + q) * 64];
            uint4 r1q = wt[(3 * 4 + q) * 64];
            uint4 hvA = hpA[q], rvA = hpA[4 + q];
            uint4 hvB = hpB[q], rvB = hpB[4 + q];
            asA0 = __builtin_amdgcn_fdot2(u2h(hvA.x), u2h(w0q.x), asA0, false);
            asA1 = __builtin_amdgcn_fdot2(u2h(hvA.x), u2h(w1q.x), asA1, false);
            asB0 = __builtin_amdgcn_fdot2(u2h(hvB.x), u2h(w0q.x), asB0, false);
            asB1 = __builtin_amdgcn_fdot2(u2h(hvB.x), u2h(w1q.x), asB1, false);
            asA0 = __builtin_amdgcn_fdot2(u2h(hvA.y), u2h(w0q.y), asA0, false);
            asA1 = __builtin_amdgcn_fdot2(u2h(hvA.y), u2h(w1q.y), asA1, false);
            asB0 = __builtin_amdgcn_fdot2(u2h(hvB.y), u2h(w0q.y), asB0, false);
            asB1 = __builtin_amdgcn_fdot2(u2h(hvB.y), u2h(w1q.y), asB1, false);
            asA0 = __builtin_amdgcn_fdot2(u2h(hvA.z), u2h(w0q.z), asA0, false);
            asA1 = __builtin_amdgcn_fdot2(u2h(hvA.z), u2h(w1q.z), asA1, false);
            asB0 = __builtin_amdgcn_fdot2(u2h(hvB.z), u2h(w0q.z), asB0, false);
            asB1 = __builtin_amdgcn_fdot2(u2h(hvB.z), u2h(w1q.z), asB1, false);
            asA0 = __builtin_amdgcn_fdot2(u2h(hvA.w), u2h(w0q.w), asA0, false);
            asA1 = __builtin_amdgcn_fdot2(u2h(hvA.w), u2h(w1q.w), asA1, false);
            asB0 = __builtin_amdgcn_fdot2(u2h(hvB.w), u2h(w0q.w), asB0, false);
            asB1 = __builtin_amdgcn_fdot2(u2h(hvB.w), u2h(w1q.w), asB1, false);
            arA0 = __builtin_amdgcn_fdot2(u2h(rvA.x), u2h(r0q.x), arA0, false);
            arA1 = __builtin_amdgcn_fdot2(u2h(rvA.x), u2h(r1q.x), arA1, false);
            arB0 = __builtin_amdgcn_fdot2(u2h(rvB.x), u2h(r0q.x), arB0, false);
            arB1 = __builtin_amdgcn_fdot2(u2h(rvB.x), u2h(r1q.x), arB1, false);
            arA0 = __builtin_amdgcn_fdot2(u2h(rvA.y), u2h(r0q.y), arA0, false);
            arA1 = __builtin_amdgcn_fdot2(u2h(rvA.y), u2h(r1q.y), arA1, false);
            arB0 = __builtin_amdgcn_fdot2(u2h(rvB.y), u2h(r0q.y), arB0, false);
            arB1 = __builtin_amdgcn_fdot2(u2h(rvB.y), u2h(r1q.y), arB1, false);
            arA0 = __builtin_amdgcn_fdot2(u2h(rvA.z), u2h(r0q.z), arA0, false);
            arA1 = __builtin_amdgcn_fdot2(u2h(rvA.z), u2h(r1q.z), arA1, false);
            arB0 = __builtin_amdgcn_fdot2(u2h(rvB.z), u2h(r0q.z), arB0, false);
            arB1 = __builtin_amdgcn_fdot2(u2h(rvB.z), u2h(r1q.z), arB1, false);
            arA0 = __builtin_amdgcn_fdot2(u2h(rvA.w), u2h(r0q.w), arA0, false);
            arA1 = __builtin_amdgcn_fdot2(u2h(rvA.w), u2h(r1q.w), arA1, false);
            arB0 = __builtin_amdgcn_fdot2(u2h(rvB.w), u2h(r0q.w), arB0, false);
            arB1 = __builtin_amdgcn_fdot2(u2h(rvB.w), u2h(r1q.w), arB1, false);
        }
        // ---- edge A
        {
            int src = sSrc[iA];
            if (src != cur) {
                float* ab = g_accu + (size_t)cur * MROW + MOFF + 2 * l;
                #pragma unroll
                for (int k = 0; k < K; ++k) {
                    unsafeAtomicAdd(ab + k * CC,     racc0[k]);
                    unsafeAtomicAdd(ab + k * CC + 1, racc1[k]);
                    racc0[k] = 0.f; racc1[k] = 0.f;
                }
                cur = src;
            }
            float2 xj = nf2[(size_t)sDst[iA] * 64 + l];
            float u0 = asA0 * arA0 * xj.x;
            float u1 = asA1 * arA1 * xj.y;
            #pragma unroll
            for (int k = 0; k < K; ++k) {
                float yv = sY[iA][YB + k];
                racc0[k] = fmaf(u0, yv, racc0[k]);
                racc1[k] = fmaf(u1, yv, racc1[k]);
            }
        }
        // ---- edge B
        {
            int src = sSrc[iB];
            if (src != cur) {
                float* ab = g_accu + (size_t)cur * MROW + MOFF + 2 * l;
                #pragma unroll
                for (int k = 0; k < K; ++k) {
                    unsafeAtomicAdd(ab + k * CC,     racc0[k]);
                    unsafeAtomicAdd(ab + k * CC + 1, racc1[k]);
                    racc0[k] = 0.f; racc1[k] = 0.f;
                }
                cur = src;
            }
            float2 xj = nf2[(size_t)sDst[iB] * 64 + l];
            float u0 = asB0 * arB0 * xj.x;
            float u1 = asB1 * arB1 * xj.y;
            #pragma unroll
            for (int k = 0; k < K; ++k) {
                float yv = sY[iB][YB + k];
                racc0[k] = fmaf(u0, yv, racc0[k]);
                racc1[k] = fmaf(u1, yv, racc1[k]);
            }
        }
    }
    float* ab = g_accu + (size_t)cur * MROW + MOFF + 2 * l;
    #pragma unroll
    for (int k = 0; k < K; ++k) {
        unsafeAtomicAdd(ab + k * CC,     racc0[k]);
        unsafeAtomicAdd(ab + k * CC + 1, racc1[k]);
    }
}

// Fused edge MLP2 + tensor-product message + segment-sum. (unchanged shell)
__global__ __launch_bounds__(192, 4) void fused_kernel(
    const float* __restrict__ nf,
    const float* __restrict__ edge_attr,
    const float* __restrict__ edge_rsh,
    const int*   __restrict__ edge_index,
    const float* __restrict__ bs2,
    const float* __restrict__ Wr1, const float* __restrict__ br1,
    const float* __restrict__ br2)
{
    __shared__ unsigned int sH[EPB][36];   // 9.2 KB packed f16 pairs
    __shared__ float sY[EPB][9];           // 2.3 KB
    __shared__ int   sSrc[EPB], sDst[EPB];

    int tid = threadIdx.x;
    int w = tid / 64;               // wave id = section id
    int l = tid & 63;
    int p = blockIdx.x * EPB + l;   // grid exact: EE/EPB
    int e = g_ord[p];

    if (w == 0) {
        int s = edge_index[e];
        int t = edge_index[EE + e];
        const float4* pi = reinterpret_cast<const float4*>(g_proj + (size_t)s * 64);
        const float4* pj = reinterpret_cast<const float4*>(g_proj + (size_t)t * 64 + HIDD);
        #pragma unroll
        for (int j4 = 0; j4 < HIDD / 8; ++j4) {
            float4 a0 = pi[2 * j4],     b0 = pj[2 * j4];
            float4 a1 = pi[2 * j4 + 1], b1 = pj[2 * j4 + 1];
            sH[l][4 * j4 + 0] = pack_h2(silu_f(a0.x + b0.x), silu_f(a0.y + b0.y));
            sH[l][4 * j4 + 1] = pack_h2(silu_f(a0.z + b0.z), silu_f(a0.w + b0.w));
            sH[l][4 * j4 + 2] = pack_h2(silu_f(a1.x + b1.x), silu_f(a1.y + b1.y));
            sH[l][4 * j4 + 3] = pack_h2(silu_f(a1.z + b1.z), silu_f(a1.w + b1.w));
        }
        sSrc[l] = s;
        sDst[l] = t;
    } else if (w == 1) {
        float hr[HIDD];
        #pragma unroll
        for (int j = 0; j < HIDD; ++j) hr[j] = br1[j];
        #pragma unroll 1
        for (int k4 = 0; k4 < RBFD / 4; ++k4) {
            float4 a = reinterpret_cast<const float4*>(edge_attr + (size_t)e * RBFD)[k4];
            const float* wp = Wr1 + (4 * k4) * HIDD;
            #pragma unroll
            for (int j = 0; j < HIDD; ++j) {
                hr[j] = fmaf(a.x, wp[j], hr[j]);
                hr[j] = fmaf(a.y, wp[HIDD + j], hr[j]);
                hr[j] = fmaf(a.z, wp[2 * HIDD + j], hr[j]);
                hr[j] = fmaf(a.w, wp[3 * HIDD + j], hr[j]);
            }
        }
        #pragma unroll
        for (int pp = 0; pp < 16; ++pp)
            sH[l][16 + pp] = pack_h2(silu_f(hr[2 * pp]), silu_f(hr[2 * pp + 1]));
    } else {
        #pragma unroll
        for (int i = 0; i < 9; ++i) sY[l][i] = edge_rsh[(size_t)e * 9 + i];
    }
    __syncthreads();

    const float2* nf2 = reinterpret_cast<const float2*>(nf);
    if (w == 0)
        section_pass<1, 0, 0>     (0, l, nf2, bs2, br2, sH, sY, sSrc, sDst);
    else if (w == 1)
        section_pass<3, 1, CC>    (1, l, nf2, bs2, br2, sH, sY, sSrc, sDst);
    else
        section_pass<5, 4, 4 * CC>(2, l, nf2, bs2, br2, sH, sY, sSrc, sDst);
}

// Node-wise linear via f16 dot2: 8 nodes per block; re-zeroes g_accu.
__global__ __launch_bounds__(256) void lin2_kernel(
    const float* __restrict__ b0, float* __restrict__ out)
{
    __shared__ unsigned int sAp[8][64][12];   // [node][c2][m(9)+pad] = 24.6 KB

    int tid = threadIdx.x;
    int n0 = blockIdx.x * 8;         // grid exact: NN/8
    float4* g = reinterpret_cast<float4*>(g_accu + (size_t)n0 * MROW);
    const float4 z4 = make_float4(0.f, 0.f, 0.f, 0.f);
    for (int i = tid; i < 8 * MROW / 4; i += 256) {
        float4 v = g[i];
        g[i] = z4;                   // restore zero for next call
        int node = i / 288;          // MROW/4 = 288 float4 per node
        int rem  = i - node * 288;
        int m  = rem >> 5;
        int c4 = rem & 31;
        sAp[node][2 * c4][m]     = pack_h2(v.x, v.y);
        sAp[node][2 * c4 + 1][m] = pack_h2(v.z, v.w);
    }
    __syncthreads();

    int d  = tid & 127;
    int nl = tid >> 7;

    float acc[4][9];
    #pragma unroll
    for (int q = 0; q < 4; ++q)
        #pragma unroll
        for (int m = 0; m < 9; ++m) acc[q][m] = 0.f;

    #pragma unroll 2
    for (int c2 = 0; c2 < 64; ++c2) {
        unsigned int wl0 = g_lw[(0 * 64 + c2) * 128 + d];
        unsigned int wl1 = g_lw[(1 * 64 + c2) * 128 + d];
        unsigned int wl2 = g_lw[(2 * 64 + c2) * 128 + d];
        #pragma unroll
        for (int q = 0; q < 4; ++q) {
            const unsigned int* ap = &sAp[nl * 4 + q][c2][0];
            uint4 a03 = *reinterpret_cast<const uint4*>(ap);       // m=0..3
            uint4 a47 = *reinterpret_cast<const uint4*>(ap + 4);   // m=4..7
            unsigned int a8 = ap[8];                               // m=8
            acc[q][0] = __builtin_amdgcn_fdot2(u2h(a03.x), u2h(wl0), acc[q][0], false);
            acc[q][1] = __builtin_amdgcn_fdot2(u2h(a03.y), u2h(wl1), acc[q][1], false);
            acc[q][2] = __builtin_amdgcn_fdot2(u2h(a03.z), u2h(wl1), acc[q][2], false);
            acc[q][3] = __builtin_amdgcn_fdot2(u2h(a03.w), u2h(wl1), acc[q][3], false);
            acc[q][4] = __builtin_amdgcn_fdot2(u2h(a47.x), u2h(wl2), acc[q][4], false);
            acc[q][5] = __builtin_amdgcn_fdot2(u2h(a47.y), u2h(wl2), acc[q][5], false);
            acc[q][6] = __builtin_amdgcn_fdot2(u2h(a47.z), u2h(wl2), acc[q][6], false);
            acc[q][7] = __builtin_amdgcn_fdot2(u2h(a47.w), u2h(wl2), acc[q][7], false);
            acc[q][8] = __builtin_amdgcn_fdot2(u2h(a8),    u2h(wl2), acc[q][8], false);
        }
    }

    const float inv = 0.08838834764831845f;  // 1/sqrt(128)
    #pragma unroll
    for (int q = 0; q < 4; ++q) {
        size_t ob = (size_t)(n0 + nl * 4 + q) * MROW;
        out[ob + d] = acc[q][0] * inv + b0[d];
        #pragma unroll
        for (int m = 0; m < 3; ++m) out[ob + CC + d * 3 + m]     = acc[q][1 + m] * inv;
        #pragma unroll
        for (int m = 0; m < 5; ++m) out[ob + 4 * CC + d * 5 + m] = acc[q][4 + m] * inv;
    }
}

extern "C" void kernel_launch(void* const* d_in, const int* in_sizes, int n_in,
                              void* d_out, int out_size, void* d_ws, size_t ws_size,
                              hipStream_t stream)
{
    const float* node_feat  = (const float*)d_in[0];
    const float* edge_attr  = (const float*)d_in[1];
    const float* edge_rsh   = (const float*)d_in[2];
    const int*   edge_index = (const int*)  d_in[3];
    const float* Ws1 = (const float*)d_in[4];
    const float* bs1 = (const float*)d_in[5];
    const float* Ws2 = (const float*)d_in[6];
    const float* bs2 = (const float*)d_in[7];
    const float* Wr1 = (const float*)d_in[8];
    const float* br1 = (const float*)d_in[9];
    const float* Wr2 = (const float*)d_in[10];
    const float* br2 = (const float*)d_in[11];
    const float* W0  = (const float*)d_in[12];
    const float* b0  = (const float*)d_in[13];
    const float* W1  = (const float*)d_in[14];
    const float* W2  = (const float*)d_in[15];
    float* out = (float*)d_out;

    pack_kernel<<<1, 192, 0, stream>>>(Ws2, Wr2, W0, W1, W2);  // also zeroes g_deg
    hist_kernel<<<EE / 256, 256, 0, stream>>>(edge_index);
    scan_kernel<<<1, 1024, 0, stream>>>();
    proj_kernel<<<NN / 16, 256, 0, stream>>>(node_feat, Ws1, bs1, edge_index);
    fused_kernel<<<EE / EPB, 192, 0, stream>>>(
        node_feat, edge_attr, edge_rsh, edge_index,
        bs2, Wr1, br1, br2);
    lin2_kernel<<<NN / 8, 256, 0, stream>>>(b0, out);
}

// Round 28
// 247.048 us; speedup vs baseline: 2.0019x; 2.0019x over previous
//
#include <hip/hip_runtime.h>
#include <hip/hip_bf16.h>
#include <math.h>

#define NN   10000
#define EE   160000
#define CC   128
#define RBFD 20
#define HIDD 32
#define WND  384
#define MROW 1152   // 9*128 accumulator row: [m=0..8][c=0..127]
#define EPB  64     // edges per block

typedef _Float16 half2_t __attribute__((ext_vector_type(2)));

__device__ __forceinline__ half2_t u2h(unsigned int u)
{
    union { unsigned int u; half2_t h; } c; c.u = u; return c.h;
}
__device__ __forceinline__ unsigned int pack_h2(float a, float b)
{
    union { half2_t h; unsigned int u; } c;
    c.h.x = (_Float16)a; c.h.y = (_Float16)b; return c.u;
}

// Static device buffers. g_accu: starts zero (.bss); each call accumulates,
// lin2 re-zeroes after reading -> invariant "zero at call entry" holds.
__device__ __align__(16) float g_proj[(size_t)NN * 64];   // 2.6 MB
__device__ __align__(16) float g_accu[(size_t)NN * MROW]; // 46 MB
__device__ __align__(16) uint4 g_wp[3 * 16 * 64];         // 48 KB packed MLP2 weights
__device__ __align__(16) unsigned int g_lw[3 * 64 * 128]; // 96 KB packed lin2 weights
__device__ int g_deg[NN];
__device__ int g_offs[NN + 1];
__device__ int g_rel[EE];
__device__ int g_ord[EE];   // sorted row -> original edge

__device__ __forceinline__ float silu_f(float x) { return x / (1.f + __expf(-x)); }

// Pack MLP2 weights (layout [sec][kind][q][lane]) + lin2 weights
// (g_lw[(mat*64+c2)*128+d] = pack(Wm[2c2][d], Wm[2c2+1][d])) + zero g_deg.
__global__ __launch_bounds__(192) void pack_kernel(
    const float* __restrict__ Ws2, const float* __restrict__ Wr2,
    const float* __restrict__ W0, const float* __restrict__ W1,
    const float* __restrict__ W2)
{
    int tid = threadIdx.x;          // 192 = 3 sec x 64 lanes
    for (int i = tid; i < NN; i += 192) g_deg[i] = 0;

    // lin2 weight packing
    for (int idx = tid; idx < 3 * 64 * 128; idx += 192) {
        int mat = idx >> 13;        // /8192
        int rem = idx & 8191;
        int c2 = rem >> 7;
        int d  = rem & 127;
        const float* Wm = (mat == 0) ? W0 : ((mat == 1) ? W1 : W2);
        g_lw[idx] = pack_h2(Wm[(2 * c2) * CC + d], Wm[(2 * c2 + 1) * CC + d]);
    }

    int sec = tid >> 6, l = tid & 63;
    int c0 = sec * 128 + 2 * l;
    #pragma unroll
    for (int q = 0; q < 4; ++q) {
        unsigned int w0[4], w1[4], r0[4], r1[4];
        #pragma unroll
        for (int i = 0; i < 4; ++i) {
            int p = 4 * q + i;
            int b0 = (2 * p) * WND + c0;
            int b1 = (2 * p + 1) * WND + c0;
            w0[i] = pack_h2(Ws2[b0],     Ws2[b1]);
            w1[i] = pack_h2(Ws2[b0 + 1], Ws2[b1 + 1]);
            r0[i] = pack_h2(Wr2[b0],     Wr2[b1]);
            r1[i] = pack_h2(Wr2[b0 + 1], Wr2[b1 + 1]);
        }
        g_wp[((sec * 16 + 0 * 4 + q) * 64) + l] = make_uint4(w0[0], w0[1], w0[2], w0[3]);
        g_wp[((sec * 16 + 1 * 4 + q) * 64) + l] = make_uint4(w1[0], w1[1], w1[2], w1[3]);
        g_wp[((sec * 16 + 2 * 4 + q) * 64) + l] = make_uint4(r0[0], r0[1], r0[2], r0[3]);
        g_wp[((sec * 16 + 3 * 4 + q) * 64) + l] = make_uint4(r1[0], r1[1], r1[2], r1[3]);
    }
}

__global__ __launch_bounds__(256) void hist_kernel(const int* __restrict__ edge_index)
{
    int e = blockIdx.x * 256 + threadIdx.x;
    if (e < EE) g_rel[e] = atomicAdd(&g_deg[edge_index[e]], 1);
}

// Blocked scan: 1024 threads x 10 items, one block.
__global__ __launch_bounds__(1024) void scan_kernel()
{
    __shared__ int sP[1024];
    int t = threadIdx.x;
    int lo = t * 10, hi = min(lo + 10, NN);
    int sum = 0;
    for (int i = lo; i < hi; ++i) sum += g_deg[i];
    sP[t] = sum;
    __syncthreads();
    for (int off = 1; off < 1024; off <<= 1) {
        int v = (t >= off) ? sP[t - off] : 0;
        __syncthreads();
        sP[t] += v;
        __syncthreads();
    }
    int run = sP[t] - sum;   // exclusive prefix
    if (t == 0) g_offs[0] = 0;
    for (int i = lo; i < hi; ++i) { run += g_deg[i]; g_offs[i + 1] = run; }
}

// MLP1 halves + edge permutation (grid is exactly EE threads).
__global__ __launch_bounds__(256) void proj_kernel(
    const float* __restrict__ nf,
    const float* __restrict__ Ws1, const float* __restrict__ bs1,
    const int* __restrict__ edge_index)
{
    __shared__ float sX[16][132];

    int tid = threadIdx.x;
    int nb = blockIdx.x * 16;       // grid exact: NN/16 = 625

    {
        int eg = blockIdx.x * 256 + tid;
        g_ord[g_offs[edge_index[eg]] + g_rel[eg]] = eg;
    }

    #pragma unroll
    for (int i = tid; i < 512; i += 256) {
        int n = i >> 5, k4 = i & 31;
        float4 v = reinterpret_cast<const float4*>(nf + (size_t)(nb + n) * CC)[k4];
        sX[n][k4 * 4 + 0] = v.x;
        sX[n][k4 * 4 + 1] = v.y;
        sX[n][k4 * 4 + 2] = v.z;
        sX[n][k4 * 4 + 3] = v.w;
    }
    __syncthreads();

    int nl = tid >> 4;
    int qd = tid & 15;
    int j0 = (qd & 7) * 4;
    int rbase = (qd >= 8) ? CC : 0;

    float4 acc;
    if (qd < 8) acc = *reinterpret_cast<const float4*>(&bs1[j0]);
    else        acc = make_float4(0.f, 0.f, 0.f, 0.f);

    const float* wb = Ws1 + (size_t)rbase * HIDD + j0;
    #pragma unroll 4
    for (int k = 0; k < CC; ++k) {
        float f = sX[nl][k];
        float4 w = *reinterpret_cast<const float4*>(wb + (size_t)k * HIDD);
        acc.x = fmaf(f, w.x, acc.x);
        acc.y = fmaf(f, w.y, acc.y);
        acc.z = fmaf(f, w.z, acc.z);
        acc.w = fmaf(f, w.w, acc.w);
    }

    float* o = g_proj + (size_t)(nb + nl) * 64 + ((qd >= 8) ? HIDD : 0) + j0;
    *reinterpret_cast<float4*>(o) = acc;
}

// One 128-col section over EPB sorted edges (R23 structure: the allocator's
// verified fixed point — per-edge loop, pre-packed f16 weights, h broadcast
// b128 from LDS, per-segment register accumulation, coalesced atomics).
template<int K, int YB, int MOFF>
__device__ __forceinline__ void section_pass(
    int sec, int l,
    const float2* __restrict__ nf2,
    const float* __restrict__ bs2, const float* __restrict__ br2,
    const unsigned int (*__restrict__ sH)[36], const float (*__restrict__ sY)[9],
    const int* __restrict__ sSrc, const int* __restrict__ sDst)
{
    const uint4* wt = g_wp + (size_t)sec * 16 * 64 + l;   // stride 64 per slot
    uint4 W0q[4], W1q[4], R0q[4], R1q[4];
    #pragma unroll
    for (int q = 0; q < 4; ++q) {
        W0q[q] = wt[(0 * 4 + q) * 64];
        W1q[q] = wt[(1 * 4 + q) * 64];
        R0q[q] = wt[(2 * 4 + q) * 64];
        R1q[q] = wt[(3 * 4 + q) * 64];
    }

    float2 bsv = *reinterpret_cast<const float2*>(&bs2[sec * 128 + 2 * l]);
    float2 brv = *reinterpret_cast<const float2*>(&br2[sec * 128 + 2 * l]);

    float racc0[K], racc1[K];
    #pragma unroll
    for (int k = 0; k < K; ++k) { racc0[k] = 0.f; racc1[k] = 0.f; }
    int cur = sSrc[0];
    float2 xjn = nf2[(size_t)sDst[0] * 64 + l];

    #pragma unroll 2
    for (int ee = 0; ee < EPB; ++ee) {
        int src = sSrc[ee];                       // broadcast -> wave-uniform
        if (src != cur) {
            float* ab = g_accu + (size_t)cur * MROW + MOFF + 2 * l;
            #pragma unroll
            for (int k = 0; k < K; ++k) {
                unsafeAtomicAdd(ab + k * CC,     racc0[k]);
                unsafeAtomicAdd(ab + k * CC + 1, racc1[k]);
                racc0[k] = 0.f; racc1[k] = 0.f;
            }
            cur = src;
        }
        float2 xj = xjn;
        xjn = nf2[(size_t)sDst[(ee + 1) & (EPB - 1)] * 64 + l];   // prefetch next
        const uint4* hp = reinterpret_cast<const uint4*>(&sH[ee][0]);
        float as0 = bsv.x, as1 = bsv.y, ar0 = brv.x, ar1 = brv.y;
        #pragma unroll
        for (int q = 0; q < 4; ++q) {
            uint4 hv = hp[q];       // hs pairs (broadcast)
            uint4 rv = hp[4 + q];   // hr pairs
            as0 = __builtin_amdgcn_fdot2(u2h(hv.x), u2h(W0q[q].x), as0, false);
            as1 = __builtin_amdgcn_fdot2(u2h(hv.x), u2h(W1q[q].x), as1, false);
            as0 = __builtin_amdgcn_fdot2(u2h(hv.y), u2h(W0q[q].y), as0, false);
            as1 = __builtin_amdgcn_fdot2(u2h(hv.y), u2h(W1q[q].y), as1, false);
            as0 = __builtin_amdgcn_fdot2(u2h(hv.z), u2h(W0q[q].z), as0, false);
            as1 = __builtin_amdgcn_fdot2(u2h(hv.z), u2h(W1q[q].z), as1, false);
            as0 = __builtin_amdgcn_fdot2(u2h(hv.w), u2h(W0q[q].w), as0, false);
            as1 = __builtin_amdgcn_fdot2(u2h(hv.w), u2h(W1q[q].w), as1, false);
            ar0 = __builtin_amdgcn_fdot2(u2h(rv.x), u2h(R0q[q].x), ar0, false);
            ar1 = __builtin_amdgcn_fdot2(u2h(rv.x), u2h(R1q[q].x), ar1, false);
            ar0 = __builtin_amdgcn_fdot2(u2h(rv.y), u2h(R0q[q].y), ar0, false);
            ar1 = __builtin_amdgcn_fdot2(u2h(rv.y), u2h(R1q[q].y), ar1, false);
            ar0 = __builtin_amdgcn_fdot2(u2h(rv.z), u2h(R0q[q].z), ar0, false);
            ar1 = __builtin_amdgcn_fdot2(u2h(rv.z), u2h(R1q[q].z), ar1, false);
            ar0 = __builtin_amdgcn_fdot2(u2h(rv.w), u2h(R0q[q].w), ar0, false);
            ar1 = __builtin_amdgcn_fdot2(u2h(rv.w), u2h(R1q[q].w), ar1, false);
        }
        float u0 = as0 * ar0 * xj.x;
        float u1 = as1 * ar1 * xj.y;
        #pragma unroll
        for (int k = 0; k < K; ++k) {
            float yv = sY[ee][YB + k];
            racc0[k] = fmaf(u0, yv, racc0[k]);
            racc1[k] = fmaf(u1, yv, racc1[k]);
        }
    }
    float* ab = g_accu + (size_t)cur * MROW + MOFF + 2 * l;
    #pragma unroll
    for (int k = 0; k < K; ++k) {
        unsafeAtomicAdd(ab + k * CC,     racc0[k]);
        unsafeAtomicAdd(ab + k * CC + 1, racc1[k]);
    }
}

// Fused edge MLP2 + tensor-product message + segment-sum.
// 192-thr block = 3 waves sharing one 64-edge tile; wave = section.
__global__ __launch_bounds__(192, 4) void fused_kernel(
    const float* __restrict__ nf,
    const float* __restrict__ edge_attr,
    const float* __restrict__ edge_rsh,
    const int*   __restrict__ edge_index,
    const float* __restrict__ bs2,
    const float* __restrict__ Wr1, const float* __restrict__ br1,
    const float* __restrict__ br2)
{
    __shared__ unsigned int sH[EPB][36];   // 9.2 KB packed f16 pairs
    __shared__ float sY[EPB][9];           // 2.3 KB
    __shared__ int   sSrc[EPB], sDst[EPB];

    int tid = threadIdx.x;
    int w = tid / 64;               // wave id = section id
    int l = tid & 63;
    int p = blockIdx.x * EPB + l;   // grid exact: EE/EPB
    int e = g_ord[p];

    if (w == 0) {
        int s = edge_index[e];
        int t = edge_index[EE + e];
        const float4* pi = reinterpret_cast<const float4*>(g_proj + (size_t)s * 64);
        const float4* pj = reinterpret_cast<const float4*>(g_proj + (size_t)t * 64 + HIDD);
        #pragma unroll
        for (int j4 = 0; j4 < HIDD / 8; ++j4) {
            float4 a0 = pi[2 * j4],     b0 = pj[2 * j4];
            float4 a1 = pi[2 * j4 + 1], b1 = pj[2 * j4 + 1];
            sH[l][4 * j4 + 0] = pack_h2(silu_f(a0.x + b0.x), silu_f(a0.y + b0.y));
            sH[l][4 * j4 + 1] = pack_h2(silu_f(a0.z + b0.z), silu_f(a0.w + b0.w));
            sH[l][4 * j4 + 2] = pack_h2(silu_f(a1.x + b1.x), silu_f(a1.y + b1.y));
            sH[l][4 * j4 + 3] = pack_h2(silu_f(a1.z + b1.z), silu_f(a1.w + b1.w));
        }
        sSrc[l] = s;
        sDst[l] = t;
    } else if (w == 1) {
        float hr[HIDD];
        #pragma unroll
        for (int j = 0; j < HIDD; ++j) hr[j] = br1[j];
        #pragma unroll 1
        for (int k4 = 0; k4 < RBFD / 4; ++k4) {
            float4 a = reinterpret_cast<const float4*>(edge_attr + (size_t)e * RBFD)[k4];
            const float* wp = Wr1 + (4 * k4) * HIDD;
            #pragma unroll
            for (int j = 0; j < HIDD; ++j) {
                hr[j] = fmaf(a.x, wp[j], hr[j]);
                hr[j] = fmaf(a.y, wp[HIDD + j], hr[j]);
                hr[j] = fmaf(a.z, wp[2 * HIDD + j], hr[j]);
                hr[j] = fmaf(a.w, wp[3 * HIDD + j], hr[j]);
            }
        }
        #pragma unroll
        for (int pp = 0; pp < 16; ++pp)
            sH[l][16 + pp] = pack_h2(silu_f(hr[2 * pp]), silu_f(hr[2 * pp + 1]));
    } else {
        #pragma unroll
        for (int i = 0; i < 9; ++i) sY[l][i] = edge_rsh[(size_t)e * 9 + i];
    }
    __syncthreads();

    const float2* nf2 = reinterpret_cast<const float2*>(nf);
    if (w == 0)
        section_pass<1, 0, 0>     (0, l, nf2, bs2, br2, sH, sY, sSrc, sDst);
    else if (w == 1)
        section_pass<3, 1, CC>    (1, l, nf2, bs2, br2, sH, sY, sSrc, sDst);
    else
        section_pass<5, 4, 4 * CC>(2, l, nf2, bs2, br2, sH, sY, sSrc, sDst);
}

// Node-wise linear via f16 dot2: 8 nodes per block; accu staged as packed
// f16 pairs (broadcast reads); pre-packed weights; re-zeroes g_accu.
__global__ __launch_bounds__(256) void lin2_kernel(
    const float* __restrict__ b0, float* __restrict__ out)
{
    __shared__ unsigned int sAp[8][64][12];   // [node][c2][m(9)+pad] = 24.6 KB

    int tid = threadIdx.x;
    int n0 = blockIdx.x * 8;         // grid exact: NN/8
    float4* g = reinterpret_cast<float4*>(g_accu + (size_t)n0 * MROW);
    const float4 z4 = make_float4(0.f, 0.f, 0.f, 0.f);
    for (int i = tid; i < 8 * MROW / 4; i += 256) {
        float4 v = g[i];
        g[i] = z4;                   // restore zero for next call
        int node = i / 288;          // MROW/4 = 288 float4 per node
        int rem  = i - node * 288;
        int m  = rem >> 5;           // /32
        int c4 = rem & 31;
        sAp[node][2 * c4][m]     = pack_h2(v.x, v.y);
        sAp[node][2 * c4 + 1][m] = pack_h2(v.z, v.w);
    }
    __syncthreads();

    int d  = tid & 127;
    int nl = tid >> 7;               // 0/1 -> nodes nl*4 .. nl*4+3

    float acc[4][9];
    #pragma unroll
    for (int q = 0; q < 4; ++q)
        #pragma unroll
        for (int m = 0; m < 9; ++m) acc[q][m] = 0.f;

    #pragma unroll 2
    for (int c2 = 0; c2 < 64; ++c2) {
        unsigned int wl0 = g_lw[(0 * 64 + c2) * 128 + d];
        unsigned int wl1 = g_lw[(1 * 64 + c2) * 128 + d];
        unsigned int wl2 = g_lw[(2 * 64 + c2) * 128 + d];
        #pragma unroll
        for (int q = 0; q < 4; ++q) {
            const unsigned int* ap = &sAp[nl * 4 + q][c2][0];
            uint4 a03 = *reinterpret_cast<const uint4*>(ap);       // m=0..3
            uint4 a47 = *reinterpret_cast<const uint4*>(ap + 4);   // m=4..7
            unsigned int a8 = ap[8];                               // m=8
            acc[q][0] = __builtin_amdgcn_fdot2(u2h(a03.x), u2h(wl0), acc[q][0], false);
            acc[q][1] = __builtin_amdgcn_fdot2(u2h(a03.y), u2h(wl1), acc[q][1], false);
            acc[q][2] = __builtin_amdgcn_fdot2(u2h(a03.z), u2h(wl1), acc[q][2], false);
            acc[q][3] = __builtin_amdgcn_fdot2(u2h(a03.w), u2h(wl1), acc[q][3], false);
            acc[q][4] = __builtin_amdgcn_fdot2(u2h(a47.x), u2h(wl2), acc[q][4], false);
            acc[q][5] = __builtin_amdgcn_fdot2(u2h(a47.y), u2h(wl2), acc[q][5], false);
            acc[q][6] = __builtin_amdgcn_fdot2(u2h(a47.z), u2h(wl2), acc[q][6], false);
            acc[q][7] = __builtin_amdgcn_fdot2(u2h(a47.w), u2h(wl2), acc[q][7], false);
            acc[q][8] = __builtin_amdgcn_fdot2(u2h(a8),    u2h(wl2), acc[q][8], false);
        }
    }

    const float inv = 0.08838834764831845f;  // 1/sqrt(128)
    #pragma unroll
    for (int q = 0; q < 4; ++q) {
        size_t ob = (size_t)(n0 + nl * 4 + q) * MROW;
        out[ob + d] = acc[q][0] * inv + b0[d];
        #pragma unroll
        for (int m = 0; m < 3; ++m) out[ob + CC + d * 3 + m]     = acc[q][1 + m] * inv;
        #pragma unroll
        for (int m = 0; m < 5; ++m) out[ob + 4 * CC + d * 5 + m] = acc[q][4 + m] * inv;
    }
}

extern "C" void kernel_launch(void* const* d_in, const int* in_sizes, int n_in,
                              void* d_out, int out_size, void* d_ws, size_t ws_size,
                              hipStream_t stream)
{
    const float* node_feat  = (const float*)d_in[0];
    const float* edge_attr  = (const float*)d_in[1];
    const float* edge_rsh   = (const float*)d_in[2];
    const int*   edge_index = (const int*)  d_in[3];
    const float* Ws1 = (const float*)d_in[4];
    const float* bs1 = (const float*)d_in[5];
    const float* Ws2 = (const float*)d_in[6];
    const float* bs2 = (const float*)d_in[7];
    const float* Wr1 = (const float*)d_in[8];
    const float* br1 = (const float*)d_in[9];
    const float* Wr2 = (const float*)d_in[10];
    const float* br2 = (const float*)d_in[11];
    const float* W0  = (const float*)d_in[12];
    const float* b0  = (const float*)d_in[13];
    const float* W1  = (const float*)d_in[14];
    const float* W2  = (const float*)d_in[15];
    float* out = (float*)d_out;

    pack_kernel<<<1, 192, 0, stream>>>(Ws2, Wr2, W0, W1, W2);  // also zeroes g_deg
    hist_kernel<<<EE / 256, 256, 0, stream>>>(edge_index);
    scan_kernel<<<1, 1024, 0, stream>>>();
    proj_kernel<<<NN / 16, 256, 0, stream>>>(node_feat, Ws1, bs1, edge_index);
    fused_kernel<<<EE / EPB, 192, 0, stream>>>(
        node_feat, edge_attr, edge_rsh, edge_index,
        bs2, Wr1, br1, br2);
    lin2_kernel<<<NN / 8, 256, 0, stream>>>(b0, out);
}